// Round 3
// baseline (626.527 us; speedup 1.0000x reference)
//
#include <hip/hip_runtime.h>

// LinearAttention on MI355X.  Inputs fp32, output fp32 (reference dtypes).
// Algebraic reformulation: final_b = N_b · x_b + bias, where
//   N_b = (W_out ⊙ ctx_b) · W_q   (per-batch 256x256),
//   ctx_b[h] = softmax_n(K) · V^T (128x128 per (b,h)).
// q and the 512-ch "out" tensor are never materialized.
//
// ws layout (bytes):
//   kv   bf16 [8][1024][4096]            @ 0          (67,108,864)
//   ctxp f32  [4][8*4][128][128]         @ 67108864   ( 8,388,608)  split-K partials
//   M    f32  [8][256][512]              @ 75497472   ( 4,194,304)
//   N    f32  [8][256][256]              @ 79691776   ( 2,097,152)
// total 81,788,928 B

#define TILE 64
#define BK 16

__device__ __forceinline__ float bf2f(unsigned short u) {
    union { unsigned int u; float f; } c;
    c.u = ((unsigned int)u) << 16;
    return c.f;
}
__device__ __forceinline__ unsigned short f2bf(float f) {
    union { float f; unsigned int u; } c; c.f = f;
    unsigned int u = c.u;
    return (unsigned short)((u + 0x7FFFu + ((u >> 16) & 1u)) >> 16);
}

// ---------------- k1: kv[b,r,n] = sum_c w_qkv[512+r,c] * x[b,c,n] ----------
__global__ __launch_bounds__(256) void k1_gemm_kv(
    const float* __restrict__ x,      // [8,256,4096] f32
    const float* __restrict__ w_qkv,  // [1536,256]  f32
    unsigned short* __restrict__ kv)  // [8,1024,4096] bf16
{
    __shared__ float As[BK][TILE + 1];  // [c][r]
    __shared__ float Bs[BK][TILE + 1];  // [c][n]
    const int tid = threadIdx.x;
    const int n0 = blockIdx.x * TILE;
    const int r0 = blockIdx.y * TILE;
    const int b  = blockIdx.z;
    const int tm = tid >> 4, tn = tid & 15;
    const int ar = tid >> 2, ac = (tid & 3) << 2;   // A: 64 rows x 16 cols
    const int br = tid >> 4, bc = (tid & 15) << 2;  // B: 16 rows x 64 cols
    const float* Ap = w_qkv + (512 + r0 + ar) * 256 + ac;
    const float* Bp = x + (b * 256 + br) * 4096 + n0 + bc;
    float acc[4][4] = {};
    for (int c0 = 0; c0 < 256; c0 += BK) {
        float4 a4 = *(const float4*)(Ap + c0);
        float4 b4 = *(const float4*)(Bp + c0 * 4096);
        As[ac + 0][ar] = a4.x; As[ac + 1][ar] = a4.y;
        As[ac + 2][ar] = a4.z; As[ac + 3][ar] = a4.w;
        Bs[br][bc + 0] = b4.x; Bs[br][bc + 1] = b4.y;
        Bs[br][bc + 2] = b4.z; Bs[br][bc + 3] = b4.w;
        __syncthreads();
        #pragma unroll
        for (int kk = 0; kk < BK; ++kk) {
            float a[4], bb[4];
            #pragma unroll
            for (int i = 0; i < 4; ++i) a[i] = As[kk][tm * 4 + i];
            #pragma unroll
            for (int j = 0; j < 4; ++j) bb[j] = Bs[kk][tn * 4 + j];
            #pragma unroll
            for (int i = 0; i < 4; ++i)
                #pragma unroll
                for (int j = 0; j < 4; ++j) acc[i][j] += a[i] * bb[j];
        }
        __syncthreads();
    }
    #pragma unroll
    for (int i = 0; i < 4; ++i) {
        ushort4 o4;
        o4.x = f2bf(acc[i][0]); o4.y = f2bf(acc[i][1]);
        o4.z = f2bf(acc[i][2]); o4.w = f2bf(acc[i][3]);
        *(ushort4*)(kv + (b * 1024 + r0 + tm * 4 + i) * 4096 + n0 + tn * 4) = o4;
    }
}

// ---------------- k2: in-place softmax over n for k rows (r in [0,512)) ----
__global__ __launch_bounds__(256) void k2_softmax(unsigned short* __restrict__ kv)
{
    __shared__ float red[4];
    const int idx = blockIdx.x;            // b*512 + r
    const int b = idx >> 9, r = idx & 511;
    unsigned short* row = kv + (b * 1024 + r) * 4096;
    const int tid = threadIdx.x;
    float v[16];
    #pragma unroll
    for (int g = 0; g < 4; ++g) {
        ushort4 u = *(const ushort4*)(row + g * 1024 + tid * 4);
        v[g * 4 + 0] = bf2f(u.x); v[g * 4 + 1] = bf2f(u.y);
        v[g * 4 + 2] = bf2f(u.z); v[g * 4 + 3] = bf2f(u.w);
    }
    float m = -1e30f;
    #pragma unroll
    for (int i = 0; i < 16; ++i) m = fmaxf(m, v[i]);
    #pragma unroll
    for (int off = 32; off > 0; off >>= 1) m = fmaxf(m, __shfl_down(m, off, 64));
    if ((tid & 63) == 0) red[tid >> 6] = m;
    __syncthreads();
    m = fmaxf(fmaxf(red[0], red[1]), fmaxf(red[2], red[3]));
    __syncthreads();
    float s = 0.f;
    #pragma unroll
    for (int i = 0; i < 16; ++i) { v[i] = __expf(v[i] - m); s += v[i]; }
    #pragma unroll
    for (int off = 32; off > 0; off >>= 1) s += __shfl_down(s, off, 64);
    if ((tid & 63) == 0) red[tid >> 6] = s;
    __syncthreads();
    s = red[0] + red[1] + red[2] + red[3];
    const float inv = 1.0f / s;
    #pragma unroll
    for (int g = 0; g < 4; ++g) {
        ushort4 u;
        u.x = f2bf(v[g * 4 + 0] * inv); u.y = f2bf(v[g * 4 + 1] * inv);
        u.z = f2bf(v[g * 4 + 2] * inv); u.w = f2bf(v[g * 4 + 3] * inv);
        *(ushort4*)(row + g * 1024 + tid * 4) = u;
    }
}

// ---------------- k3: ctxp[s][bh][d][e] = sum_{n in slice} ksm[d,n]*v[e,n] --
__global__ __launch_bounds__(256) void k3_context(
    const unsigned short* __restrict__ kv, float* __restrict__ ctxp)
{
    __shared__ float As[BK][TILE + 1];  // [n][d]
    __shared__ float Bs[BK][TILE + 1];  // [n][e]
    const int tid = threadIdx.x;
    const int s  = blockIdx.x;                       // K slice (4)
    const int d0 = (blockIdx.y >> 1) * TILE;
    const int e0 = (blockIdx.y & 1) * TILE;
    const int bh = blockIdx.z;
    const int bB = bh >> 2, h = bh & 3;
    const int tm = tid >> 4, tn = tid & 15;
    const int lr = tid >> 2, lc = (tid & 3) << 2;    // 64 rows x 16 n
    const unsigned short* Kp = kv + (bB * 1024 + h * 128 + d0 + lr) * 4096;
    const unsigned short* Vp = kv + (bB * 1024 + 512 + h * 128 + e0 + lr) * 4096;
    float acc[4][4] = {};
    const int nbeg = s * 1024;
    for (int n = nbeg; n < nbeg + 1024; n += BK) {
        ushort4 a4 = *(const ushort4*)(Kp + n + lc);
        ushort4 b4 = *(const ushort4*)(Vp + n + lc);
        As[lc + 0][lr] = bf2f(a4.x); As[lc + 1][lr] = bf2f(a4.y);
        As[lc + 2][lr] = bf2f(a4.z); As[lc + 3][lr] = bf2f(a4.w);
        Bs[lc + 0][lr] = bf2f(b4.x); Bs[lc + 1][lr] = bf2f(b4.y);
        Bs[lc + 2][lr] = bf2f(b4.z); Bs[lc + 3][lr] = bf2f(b4.w);
        __syncthreads();
        #pragma unroll
        for (int kk = 0; kk < BK; ++kk) {
            float a[4], bb[4];
            #pragma unroll
            for (int i = 0; i < 4; ++i) a[i] = As[kk][tm * 4 + i];
            #pragma unroll
            for (int j = 0; j < 4; ++j) bb[j] = Bs[kk][tn * 4 + j];
            #pragma unroll
            for (int i = 0; i < 4; ++i)
                #pragma unroll
                for (int j = 0; j < 4; ++j) acc[i][j] += a[i] * bb[j];
        }
        __syncthreads();
    }
    #pragma unroll
    for (int i = 0; i < 4; ++i) {
        float4 o; o.x = acc[i][0]; o.y = acc[i][1]; o.z = acc[i][2]; o.w = acc[i][3];
        *(float4*)(ctxp + ((s * 32 + bh) * 128 + d0 + tm * 4 + i) * 128 + e0 + tn * 4) = o;
    }
}

// ------- k4: M[b][o][h*128+d] = sum_e w_out[o,h*128+e] * (sum_s ctxp) ------
__global__ __launch_bounds__(256) void k4_m(
    const float* __restrict__ w_out,  // [256,512] f32
    const float* __restrict__ ctxp, float* __restrict__ M)
{
    __shared__ float As[BK][TILE + 1];  // [e][o]
    __shared__ float Bs[BK][TILE + 1];  // [e][d]
    const int tid = threadIdx.x;
    const int d0 = blockIdx.x * TILE;   // 0 or 64
    const int o0 = blockIdx.y * TILE;   // 0..192
    const int bh = blockIdx.z;
    const int bB = bh >> 2, h = bh & 3;
    const int tm = tid >> 4, tn = tid & 15;
    const int lr = tid >> 2, lc = (tid & 3) << 2;
    float acc[4][4] = {};
    for (int e0 = 0; e0 < 128; e0 += BK) {
        float4 a4 = *(const float4*)(w_out + (o0 + lr) * 512 + h * 128 + e0 + lc);
        float4 bsum = make_float4(0.f, 0.f, 0.f, 0.f);
        #pragma unroll
        for (int sl = 0; sl < 4; ++sl) {
            float4 t = *(const float4*)(ctxp + ((sl * 32 + bh) * 128 + d0 + lr) * 128 + e0 + lc);
            bsum.x += t.x; bsum.y += t.y; bsum.z += t.z; bsum.w += t.w;
        }
        As[lc + 0][lr] = a4.x; As[lc + 1][lr] = a4.y;
        As[lc + 2][lr] = a4.z; As[lc + 3][lr] = a4.w;
        Bs[lc + 0][lr] = bsum.x; Bs[lc + 1][lr] = bsum.y;
        Bs[lc + 2][lr] = bsum.z; Bs[lc + 3][lr] = bsum.w;
        __syncthreads();
        #pragma unroll
        for (int kk = 0; kk < BK; ++kk) {
            float a[4], bb[4];
            #pragma unroll
            for (int i = 0; i < 4; ++i) a[i] = As[kk][tm * 4 + i];
            #pragma unroll
            for (int j = 0; j < 4; ++j) bb[j] = Bs[kk][tn * 4 + j];
            #pragma unroll
            for (int i = 0; i < 4; ++i)
                #pragma unroll
                for (int j = 0; j < 4; ++j) acc[i][j] += a[i] * bb[j];
        }
        __syncthreads();
    }
    #pragma unroll
    for (int i = 0; i < 4; ++i) {
        float4 o; o.x = acc[i][0]; o.y = acc[i][1]; o.z = acc[i][2]; o.w = acc[i][3];
        *(float4*)(M + (bB * 256 + o0 + tm * 4 + i) * 512 + h * 128 + d0 + tn * 4) = o;
    }
}

// ---------- k5: N[b][o][c] = sum_{j<512} M[b][o][j] * w_qkv[j][c] ----------
__global__ __launch_bounds__(256) void k5_n(
    const float* __restrict__ M, const float* __restrict__ w_qkv,
    float* __restrict__ N)
{
    __shared__ float As[BK][TILE + 1];  // [j][o]
    __shared__ float Bs[BK][TILE + 1];  // [j][c]
    const int tid = threadIdx.x;
    const int c0 = blockIdx.x * TILE;
    const int o0 = blockIdx.y * TILE;
    const int b  = blockIdx.z;
    const int tm = tid >> 4, tn = tid & 15;
    const int lr = tid >> 2, lc = (tid & 3) << 2;
    const int br = tid >> 4, bc = (tid & 15) << 2;
    float acc[4][4] = {};
    for (int j0 = 0; j0 < 512; j0 += BK) {
        float4 a4 = *(const float4*)(M + (b * 256 + o0 + lr) * 512 + j0 + lc);
        float4 b4 = *(const float4*)(w_qkv + (j0 + br) * 256 + c0 + bc);
        As[lc + 0][lr] = a4.x; As[lc + 1][lr] = a4.y;
        As[lc + 2][lr] = a4.z; As[lc + 3][lr] = a4.w;
        Bs[br][bc + 0] = b4.x; Bs[br][bc + 1] = b4.y;
        Bs[br][bc + 2] = b4.z; Bs[br][bc + 3] = b4.w;
        __syncthreads();
        #pragma unroll
        for (int kk = 0; kk < BK; ++kk) {
            float a[4], bb[4];
            #pragma unroll
            for (int i = 0; i < 4; ++i) a[i] = As[kk][tm * 4 + i];
            #pragma unroll
            for (int j = 0; j < 4; ++j) bb[j] = Bs[kk][tn * 4 + j];
            #pragma unroll
            for (int i = 0; i < 4; ++i)
                #pragma unroll
                for (int j = 0; j < 4; ++j) acc[i][j] += a[i] * bb[j];
        }
        __syncthreads();
    }
    #pragma unroll
    for (int i = 0; i < 4; ++i) {
        float4 o; o.x = acc[i][0]; o.y = acc[i][1]; o.z = acc[i][2]; o.w = acc[i][3];
        *(float4*)(N + (b * 256 + o0 + tm * 4 + i) * 256 + c0 + tn * 4) = o;
    }
}

// -------- k6: out[b,o,n] = sum_c N[b][o][c] * x[b,c,n] + b_out[o] ----------
__global__ __launch_bounds__(256) void k6_final(
    const float* __restrict__ N, const float* __restrict__ x,
    const float* __restrict__ b_out, float* __restrict__ out)
{
    __shared__ float As[BK][TILE + 1];  // [c][o]
    __shared__ float Bs[BK][TILE + 1];  // [c][n]
    const int tid = threadIdx.x;
    const int n0 = blockIdx.x * TILE;
    const int o0 = blockIdx.y * TILE;
    const int b  = blockIdx.z;
    const int tm = tid >> 4, tn = tid & 15;
    const int lr = tid >> 2, lc = (tid & 3) << 2;
    const int br = tid >> 4, bc = (tid & 15) << 2;
    float acc[4][4] = {};
    for (int c0 = 0; c0 < 256; c0 += BK) {
        float4 a4 = *(const float4*)(N + (b * 256 + o0 + lr) * 256 + c0 + lc);
        float4 b4 = *(const float4*)(x + (b * 256 + c0 + br) * 4096 + n0 + bc);
        As[lc + 0][lr] = a4.x; As[lc + 1][lr] = a4.y;
        As[lc + 2][lr] = a4.z; As[lc + 3][lr] = a4.w;
        Bs[br][bc + 0] = b4.x; Bs[br][bc + 1] = b4.y;
        Bs[br][bc + 2] = b4.z; Bs[br][bc + 3] = b4.w;
        __syncthreads();
        #pragma unroll
        for (int kk = 0; kk < BK; ++kk) {
            float a[4], bb[4];
            #pragma unroll
            for (int i = 0; i < 4; ++i) a[i] = As[kk][tm * 4 + i];
            #pragma unroll
            for (int j = 0; j < 4; ++j) bb[j] = Bs[kk][tn * 4 + j];
            #pragma unroll
            for (int i = 0; i < 4; ++i)
                #pragma unroll
                for (int j = 0; j < 4; ++j) acc[i][j] += a[i] * bb[j];
        }
        __syncthreads();
    }
    #pragma unroll
    for (int i = 0; i < 4; ++i) {
        const float bias = b_out[o0 + tm * 4 + i];
        float4 o4;
        o4.x = acc[i][0] + bias; o4.y = acc[i][1] + bias;
        o4.z = acc[i][2] + bias; o4.w = acc[i][3] + bias;
        *(float4*)(out + (b * 256 + o0 + tm * 4 + i) * 4096 + n0 + tn * 4) = o4;
    }
}

extern "C" void kernel_launch(void* const* d_in, const int* in_sizes, int n_in,
                              void* d_out, int out_size, void* d_ws, size_t ws_size,
                              hipStream_t stream) {
    (void)in_sizes; (void)n_in; (void)out_size; (void)ws_size;
    const float* x     = (const float*)d_in[0];  // f32 [8,256,64,64]
    const float* w_qkv = (const float*)d_in[1];  // f32 [1536,256]
    const float* w_out = (const float*)d_in[2];  // f32 [256,512]
    const float* b_out = (const float*)d_in[3];  // f32 [256]
    float* out = (float*)d_out;                  // f32 [8,256,64,64]

    char* ws = (char*)d_ws;
    unsigned short* kv = (unsigned short*)ws;                      // 67,108,864 B
    float* ctxp = (float*)(ws + 67108864);                         //  8,388,608 B
    float* M    = (float*)(ws + 67108864 + 8388608);               //  4,194,304 B
    float* N    = (float*)(ws + 67108864 + 8388608 + 4194304);     //  2,097,152 B

    k1_gemm_kv<<<dim3(64, 16, 8), 256, 0, stream>>>(x, w_qkv, kv);
    k2_softmax<<<dim3(4096), 256, 0, stream>>>(kv);
    k3_context<<<dim3(4, 4, 32), 256, 0, stream>>>(kv, ctxp);
    k4_m<<<dim3(2, 4, 32), 256, 0, stream>>>(w_out, ctxp, M);
    k5_n<<<dim3(4, 4, 8), 256, 0, stream>>>(M, w_qkv, N);
    k6_final<<<dim3(64, 4, 8), 256, 0, stream>>>(N, x, b_out, out);
}

// Round 4
// 223.452 us; speedup vs baseline: 2.8039x; 2.8039x over previous
//
#include <hip/hip_runtime.h>
#include <stdint.h>

// LinearAttention on MI355X — round 4: MFMA (bf16) for the three big GEMMs.
// final_b = N_b · x_b + bias;  N_b = (W_out ⊙ ctx_b) · W_q;  ctx_b[h] = softmax_n(K)·V^T.
//
// ws layout (bytes):
//   kv    bf16 [8][1024][4096]   @ 0          (67,108,864)
//   xbT   bf16 [8][4096][256]    @ 67108864   (16,777,216)   x transposed+converted
//   wkvb  bf16 [1024][256]       @ 83886080   (   524,288)   w_qkv rows 512..1536
//   ctxp  f32  [8][32][128][128] @ 84410368   (16,777,216)   split-8 partials
//   M     f32  [8][256][512]     @ 101187584  ( 4,194,304)
//   Nb    bf16 [8][256][256]     @ 105381888  ( 1,048,576)
// total 106,430,464 B

#define TILE 64
#define BK 16

using frag8 = __attribute__((ext_vector_type(8))) short;   // 8 x bf16
using f32x4 = __attribute__((ext_vector_type(4))) float;

__device__ __forceinline__ float bf2f(unsigned short u) {
    union { unsigned int u; float f; } c;
    c.u = ((unsigned int)u) << 16;
    return c.f;
}
__device__ __forceinline__ unsigned short f2bf(float f) {
    union { float f; unsigned int u; } c; c.f = f;
    unsigned int u = c.u;
    return (unsigned short)((u + 0x7FFFu + ((u >> 16) & 1u)) >> 16);
}

__device__ __forceinline__ void gl_lds16(const void* g, void* l) {
    __builtin_amdgcn_global_load_lds(
        (const __attribute__((address_space(1))) unsigned int*)g,
        (__attribute__((address_space(3))) unsigned int*)l, 16, 0, 0);
}

// ---------------- k0a: convert w_qkv rows 512..1536 to bf16 ----------------
__global__ __launch_bounds__(256) void k0_wconv(
    const float* __restrict__ w_qkv, unsigned short* __restrict__ wkvb)
{
    const int idx = (blockIdx.x * 256 + threadIdx.x) * 4;
    float4 v = *(const float4*)(w_qkv + 512 * 256 + idx);
    ushort4 o;
    o.x = f2bf(v.x); o.y = f2bf(v.y); o.z = f2bf(v.z); o.w = f2bf(v.w);
    *(ushort4*)(wkvb + idx) = o;
}

// ---------------- k0b: xbT[b][n][c] = bf16(x[b][c][n]) --------------------
__global__ __launch_bounds__(256) void k0_xt(
    const float* __restrict__ x, unsigned short* __restrict__ xbT)
{
    __shared__ float T[64][65];
    const int tid = threadIdx.x;
    const int n0 = blockIdx.x * 64, c0 = blockIdx.y * 64, b = blockIdx.z;
    const float* xb = x + (size_t)b * 1048576;
    const int cr = tid >> 4, nc = (tid & 15) * 4;
    #pragma unroll
    for (int p = 0; p < 4; ++p) {
        float4 v = *(const float4*)(xb + (size_t)(c0 + cr + p * 16) * 4096 + n0 + nc);
        T[cr + p * 16][nc + 0] = v.x; T[cr + p * 16][nc + 1] = v.y;
        T[cr + p * 16][nc + 2] = v.z; T[cr + p * 16][nc + 3] = v.w;
    }
    __syncthreads();
    const int n = tid >> 2, cc = (tid & 3) * 16;
    unsigned short* dst = xbT + (size_t)b * 1048576 + (size_t)(n0 + n) * 256 + c0 + cc;
    #pragma unroll
    for (int g = 0; g < 4; ++g) {
        ushort4 o;
        o.x = f2bf(T[cc + g * 4 + 0][n]);
        o.y = f2bf(T[cc + g * 4 + 1][n]);
        o.z = f2bf(T[cc + g * 4 + 2][n]);
        o.w = f2bf(T[cc + g * 4 + 3][n]);
        *(ushort4*)(dst + g * 4) = o;
    }
}

// -------- MFMA gemm_bt: C[m][n] = sum_k A[m][k] * B[n][k]  (bf16 in) -------
// 128x128 block tile, BK=32, 4 waves (each 64x64), 16x16x32 bf16 MFMA.
// MODE 0: C bf16 (k1: kv).  MODE 1: C f32 + bias[row] (k6: out).
// MODE 2: k3 context — single 128x128 tile, k-slice = blockIdx.x*512.
template<int MODE>
__global__ __launch_bounds__(256) void mfma_bt(
    const unsigned short* __restrict__ A0, int lda,
    const unsigned short* __restrict__ B0, int ldb,
    void* __restrict__ C0, int ldc,
    const float* __restrict__ bias, int Kp,
    unsigned long long sAz, unsigned long long sBz, unsigned long long sCz)
{
    __shared__ unsigned short As[128 * 32];
    __shared__ unsigned short Bs[128 * 32];
    const int tid  = threadIdx.x;
    const int w    = tid >> 6, lane = tid & 63;
    const int quad = lane >> 4, l16 = lane & 15;
    const int wm = (w >> 1) * 64, wn = (w & 1) * 64;
    const int z = blockIdx.z;

    const unsigned short* A;
    const unsigned short* B;
    int ks, ke, m0, n0;
    if constexpr (MODE == 2) {
        m0 = 0; n0 = 0;
        ks = blockIdx.x * 512; ke = ks + 512;
        const unsigned long long off =
            ((unsigned long long)(z >> 2) * 1024ull + (unsigned long long)(z & 3) * 128ull) * 4096ull;
        A = A0 + off; B = B0 + off;
    } else {
        m0 = blockIdx.y * 128; n0 = blockIdx.x * 128;
        ks = 0; ke = Kp;
        A = A0 + sAz * z + (unsigned long long)m0 * lda;
        B = B0 + sBz * z + (unsigned long long)n0 * ldb;
    }

    // staging: 512 chunks of 16B per tile; wave w handles chunks [w*128, w*128+128)
    const int cA0 = w * 128 + lane;
    const int cA1 = cA0 + 64;
    const unsigned short* gA0 = A + (unsigned long long)(cA0 >> 2) * lda + (cA0 & 3) * 8;
    const unsigned short* gA1 = A + (unsigned long long)(cA1 >> 2) * lda + (cA1 & 3) * 8;
    const unsigned short* gB0 = B + (unsigned long long)(cA0 >> 2) * ldb + (cA0 & 3) * 8;
    const unsigned short* gB1 = B + (unsigned long long)(cA1 >> 2) * ldb + (cA1 & 3) * 8;
    unsigned short* lA0 = As + w * 1024;
    unsigned short* lA1 = As + w * 1024 + 512;
    unsigned short* lB0 = Bs + w * 1024;
    unsigned short* lB1 = Bs + w * 1024 + 512;

    f32x4 acc[4][4] = {};

    for (int k0 = ks; k0 < ke; k0 += 32) {
        gl_lds16(gA0 + k0, lA0);
        gl_lds16(gA1 + k0, lA1);
        gl_lds16(gB0 + k0, lB0);
        gl_lds16(gB1 + k0, lB1);
        __syncthreads();            // drains vmcnt -> LDS tiles ready
        frag8 a[4], b[4];
        #pragma unroll
        for (int t = 0; t < 4; ++t) {
            a[t] = *(const frag8*)(As + (wm + t * 16 + l16) * 32 + quad * 8);
            b[t] = *(const frag8*)(Bs + (wn + t * 16 + l16) * 32 + quad * 8);
        }
        #pragma unroll
        for (int mt = 0; mt < 4; ++mt)
            #pragma unroll
            for (int nt = 0; nt < 4; ++nt)
                acc[mt][nt] = __builtin_amdgcn_mfma_f32_16x16x32_bf16(
                    a[mt], b[nt], acc[mt][nt], 0, 0, 0);
        __syncthreads();            // protect LDS before next stage
    }

    // epilogue: C/D mapping col = lane&15, row = quad*4 + reg  [m91-verified]
    if constexpr (MODE == 0) {
        unsigned short* C = (unsigned short*)C0 + sCz * z
                          + (unsigned long long)m0 * ldc + n0;
        #pragma unroll
        for (int mt = 0; mt < 4; ++mt) {
            const int row = wm + mt * 16 + quad * 4;
            #pragma unroll
            for (int nt = 0; nt < 4; ++nt) {
                const int col = wn + nt * 16 + l16;
                #pragma unroll
                for (int r = 0; r < 4; ++r)
                    C[(unsigned long long)(row + r) * ldc + col] = f2bf(acc[mt][nt][r]);
            }
        }
    } else if constexpr (MODE == 1) {
        float* C = (float*)C0 + sCz * z + (unsigned long long)m0 * ldc + n0;
        const float* bp = bias + m0;
        #pragma unroll
        for (int mt = 0; mt < 4; ++mt) {
            const int row = wm + mt * 16 + quad * 4;
            #pragma unroll
            for (int nt = 0; nt < 4; ++nt) {
                const int col = wn + nt * 16 + l16;
                #pragma unroll
                for (int r = 0; r < 4; ++r)
                    C[(unsigned long long)(row + r) * ldc + col] = acc[mt][nt][r] + bp[row + r];
            }
        }
    } else {
        float* C = (float*)C0 + ((unsigned long long)blockIdx.x * 32 + z) * 16384ull;
        #pragma unroll
        for (int mt = 0; mt < 4; ++mt) {
            const int row = wm + mt * 16 + quad * 4;
            #pragma unroll
            for (int nt = 0; nt < 4; ++nt) {
                const int col = wn + nt * 16 + l16;
                #pragma unroll
                for (int r = 0; r < 4; ++r)
                    C[(row + r) * 128 + col] = acc[mt][nt][r];
            }
        }
    }
}

// ---------------- k2: in-place softmax over n for k rows (r in [0,512)) ----
__global__ __launch_bounds__(256) void k2_softmax(unsigned short* __restrict__ kv)
{
    __shared__ float red[4];
    const int idx = blockIdx.x;            // b*512 + r
    const int b = idx >> 9, r = idx & 511;
    unsigned short* row = kv + (size_t)(b * 1024 + r) * 4096;
    const int tid = threadIdx.x;
    float v[16];
    #pragma unroll
    for (int g = 0; g < 4; ++g) {
        ushort4 u = *(const ushort4*)(row + g * 1024 + tid * 4);
        v[g * 4 + 0] = bf2f(u.x); v[g * 4 + 1] = bf2f(u.y);
        v[g * 4 + 2] = bf2f(u.z); v[g * 4 + 3] = bf2f(u.w);
    }
    float m = -1e30f;
    #pragma unroll
    for (int i = 0; i < 16; ++i) m = fmaxf(m, v[i]);
    #pragma unroll
    for (int off = 32; off > 0; off >>= 1) m = fmaxf(m, __shfl_down(m, off, 64));
    if ((tid & 63) == 0) red[tid >> 6] = m;
    __syncthreads();
    m = fmaxf(fmaxf(red[0], red[1]), fmaxf(red[2], red[3]));
    __syncthreads();
    float s = 0.f;
    #pragma unroll
    for (int i = 0; i < 16; ++i) { v[i] = __expf(v[i] - m); s += v[i]; }
    #pragma unroll
    for (int off = 32; off > 0; off >>= 1) s += __shfl_down(s, off, 64);
    if ((tid & 63) == 0) red[tid >> 6] = s;
    __syncthreads();
    s = red[0] + red[1] + red[2] + red[3];
    const float inv = 1.0f / s;
    #pragma unroll
    for (int g = 0; g < 4; ++g) {
        ushort4 u;
        u.x = f2bf(v[g * 4 + 0] * inv); u.y = f2bf(v[g * 4 + 1] * inv);
        u.z = f2bf(v[g * 4 + 2] * inv); u.w = f2bf(v[g * 4 + 3] * inv);
        *(ushort4*)(row + g * 1024 + tid * 4) = u;
    }
}

// ------- k4: M[b][o][h*128+d] = sum_e w_out[o,h*128+e] * (sum_s ctxp) ------
__global__ __launch_bounds__(256) void k4_m(
    const float* __restrict__ w_out,  // [256,512] f32
    const float* __restrict__ ctxp, float* __restrict__ M)
{
    __shared__ float As[BK][TILE + 1];  // [e][o]
    __shared__ float Bs[BK][TILE + 1];  // [e][d]
    const int tid = threadIdx.x;
    const int d0 = blockIdx.x * TILE;   // 0 or 64
    const int o0 = blockIdx.y * TILE;   // 0..192
    const int bh = blockIdx.z;
    const int bB = bh >> 2, h = bh & 3;
    const int tm = tid >> 4, tn = tid & 15;
    const int lr = tid >> 2, lc = (tid & 3) << 2;
    float acc[4][4] = {};
    for (int e0 = 0; e0 < 128; e0 += BK) {
        float4 a4 = *(const float4*)(w_out + (o0 + lr) * 512 + h * 128 + e0 + lc);
        float4 bsum = make_float4(0.f, 0.f, 0.f, 0.f);
        #pragma unroll
        for (int sl = 0; sl < 8; ++sl) {
            float4 t = *(const float4*)(ctxp + ((size_t)(sl * 32 + bh) * 128 + d0 + lr) * 128 + e0 + lc);
            bsum.x += t.x; bsum.y += t.y; bsum.z += t.z; bsum.w += t.w;
        }
        As[lc + 0][lr] = a4.x; As[lc + 1][lr] = a4.y;
        As[lc + 2][lr] = a4.z; As[lc + 3][lr] = a4.w;
        Bs[lc + 0][lr] = bsum.x; Bs[lc + 1][lr] = bsum.y;
        Bs[lc + 2][lr] = bsum.z; Bs[lc + 3][lr] = bsum.w;
        __syncthreads();
        #pragma unroll
        for (int kk = 0; kk < BK; ++kk) {
            float a[4], bb[4];
            #pragma unroll
            for (int i = 0; i < 4; ++i) a[i] = As[kk][tm * 4 + i];
            #pragma unroll
            for (int j = 0; j < 4; ++j) bb[j] = Bs[kk][tn * 4 + j];
            #pragma unroll
            for (int i = 0; i < 4; ++i)
                #pragma unroll
                for (int j = 0; j < 4; ++j) acc[i][j] += a[i] * bb[j];
        }
        __syncthreads();
    }
    #pragma unroll
    for (int i = 0; i < 4; ++i) {
        float4 o; o.x = acc[i][0]; o.y = acc[i][1]; o.z = acc[i][2]; o.w = acc[i][3];
        *(float4*)(M + (size_t)(bB * 256 + o0 + tm * 4 + i) * 512 + h * 128 + d0 + tn * 4) = o;
    }
}

// ---------- k5: Nb[b][o][c] = bf16( sum_{j<512} M[b][o][j] * w_qkv[j][c] ) --
__global__ __launch_bounds__(256) void k5_n(
    const float* __restrict__ M, const float* __restrict__ w_qkv,
    unsigned short* __restrict__ Nb)
{
    __shared__ float As[BK][TILE + 1];  // [j][o]
    __shared__ float Bs[BK][TILE + 1];  // [j][c]
    const int tid = threadIdx.x;
    const int c0 = blockIdx.x * TILE;
    const int o0 = blockIdx.y * TILE;
    const int b  = blockIdx.z;
    const int tm = tid >> 4, tn = tid & 15;
    const int lr = tid >> 2, lc = (tid & 3) << 2;
    const int br = tid >> 4, bc = (tid & 15) << 2;
    float acc[4][4] = {};
    for (int j0 = 0; j0 < 512; j0 += BK) {
        float4 a4 = *(const float4*)(M + (size_t)(b * 256 + o0 + lr) * 512 + j0 + lc);
        float4 b4 = *(const float4*)(w_qkv + (size_t)(j0 + br) * 256 + c0 + bc);
        As[lc + 0][lr] = a4.x; As[lc + 1][lr] = a4.y;
        As[lc + 2][lr] = a4.z; As[lc + 3][lr] = a4.w;
        Bs[br][bc + 0] = b4.x; Bs[br][bc + 1] = b4.y;
        Bs[br][bc + 2] = b4.z; Bs[br][bc + 3] = b4.w;
        __syncthreads();
        #pragma unroll
        for (int kk = 0; kk < BK; ++kk) {
            float a[4], bb[4];
            #pragma unroll
            for (int i = 0; i < 4; ++i) a[i] = As[kk][tm * 4 + i];
            #pragma unroll
            for (int j = 0; j < 4; ++j) bb[j] = Bs[kk][tn * 4 + j];
            #pragma unroll
            for (int i = 0; i < 4; ++i)
                #pragma unroll
                for (int j = 0; j < 4; ++j) acc[i][j] += a[i] * bb[j];
        }
        __syncthreads();
    }
    #pragma unroll
    for (int i = 0; i < 4; ++i) {
        ushort4 o4;
        o4.x = f2bf(acc[i][0]); o4.y = f2bf(acc[i][1]);
        o4.z = f2bf(acc[i][2]); o4.w = f2bf(acc[i][3]);
        *(ushort4*)(Nb + (size_t)(b * 256 + o0 + tm * 4 + i) * 256 + c0 + tn * 4) = o4;
    }
}

extern "C" void kernel_launch(void* const* d_in, const int* in_sizes, int n_in,
                              void* d_out, int out_size, void* d_ws, size_t ws_size,
                              hipStream_t stream) {
    (void)in_sizes; (void)n_in; (void)out_size; (void)ws_size;
    const float* x     = (const float*)d_in[0];  // f32 [8,256,64,64]
    const float* w_qkv = (const float*)d_in[1];  // f32 [1536,256]
    const float* w_out = (const float*)d_in[2];  // f32 [256,512]
    const float* b_out = (const float*)d_in[3];  // f32 [256]
    float* out = (float*)d_out;                  // f32 [8,256,64,64]

    char* ws = (char*)d_ws;
    unsigned short* kv   = (unsigned short*)ws;                 // 67,108,864
    unsigned short* xbT  = (unsigned short*)(ws + 67108864);    // 16,777,216
    unsigned short* wkvb = (unsigned short*)(ws + 83886080);    //    524,288
    float*          ctxp = (float*)(ws + 84410368);             // 16,777,216
    float*          M    = (float*)(ws + 101187584);            //  4,194,304
    unsigned short* Nb   = (unsigned short*)(ws + 105381888);   //  1,048,576

    k0_wconv<<<dim3(256), 256, 0, stream>>>(w_qkv, wkvb);
    k0_xt<<<dim3(64, 4, 8), 256, 0, stream>>>(x, xbT);
    // k1: kv[b,r,n] = sum_c wkvb[r,c] * xbT[b,n,c]
    mfma_bt<0><<<dim3(32, 8, 8), 256, 0, stream>>>(
        wkvb, 256, xbT, 256, kv, 4096, nullptr, 256,
        0ull, 1048576ull, 4194304ull);
    k2_softmax<<<dim3(4096), 256, 0, stream>>>(kv);
    // k3: ctxp[s,bh,d,e] = sum_{n in slice} Ksm[d,n]*V[e,n]
    mfma_bt<2><<<dim3(8, 1, 32), 256, 0, stream>>>(
        kv, 4096, kv + (size_t)512 * 4096, 4096, ctxp, 128, nullptr, 0,
        0ull, 0ull, 0ull);
    k4_m<<<dim3(2, 4, 32), 256, 0, stream>>>(w_out, ctxp, M);
    k5_n<<<dim3(4, 4, 8), 256, 0, stream>>>(M, w_qkv, Nb);
    // k6: out[b,o,n] = sum_c Nb[b,o,c] * xbT[b,n,c] + b_out[o]
    mfma_bt<1><<<dim3(32, 2, 8), 256, 0, stream>>>(
        Nb, 256, xbT, 256, out, 4096, b_out, 256,
        65536ull, 1048576ull, 1048576ull);
}

// Round 5
// 184.483 us; speedup vs baseline: 3.3961x; 1.2112x over previous
//
#include <hip/hip_runtime.h>
#include <stdint.h>

// LinearAttention on MI355X — round 5: everything matmul-shaped goes through MFMA.
// final_b = N_b · x_b + bias;  N_b = (W_out ⊙ ctx_b) · W_q;  ctx_b[h] = softmax_n(K)·V^T.
//
// ws layout (bytes):
//   kv    bf16 [8][1024][4096]   @ 0          (67,108,864)
//   xbT   bf16 [8][4096][256]    @ 67108864   (16,777,216)
//   wkvb  bf16 [1024][256]       @ 83886080   (   524,288)
//   woutb bf16 [256][512]        @ 84410368   (   262,144)
//   wqT   bf16 [256][512]        @ 84672512   (   262,144)   W_q transposed
//   ctxp  f32  [8][32][128][128] @ 84934656   (16,777,216)   split-8 partials
//   ctxb  bf16 [32][128][128]    @ 101711872  ( 1,048,576)
//   Mb    bf16 [8][256][512]     @ 102760448  ( 2,097,152)
//   Nb    bf16 [8][256][256]     @ 104857600  ( 1,048,576)
// total 105,906,176 B

using frag8 = __attribute__((ext_vector_type(8))) short;   // 8 x bf16
using f32x4 = __attribute__((ext_vector_type(4))) float;

__device__ __forceinline__ float bf2f(unsigned short u) {
    union { unsigned int u; float f; } c;
    c.u = ((unsigned int)u) << 16;
    return c.f;
}
__device__ __forceinline__ unsigned short f2bf(float f) {
    union { float f; unsigned int u; } c; c.f = f;
    unsigned int u = c.u;
    return (unsigned short)((u + 0x7FFFu + ((u >> 16) & 1u)) >> 16);
}

__device__ __forceinline__ void gl_lds16(const void* g, void* l) {
    __builtin_amdgcn_global_load_lds(
        (const __attribute__((address_space(1))) unsigned int*)g,
        (__attribute__((address_space(3))) unsigned int*)l, 16, 0, 0);
}

// ------- k0_weights: wkvb, woutb (row-copy bf16), wqT (transpose bf16) -----
__global__ __launch_bounds__(256) void k0_weights(
    const float* __restrict__ w_qkv, const float* __restrict__ w_out,
    unsigned short* __restrict__ wkvb, unsigned short* __restrict__ woutb,
    unsigned short* __restrict__ wqT)
{
    __shared__ float T[64][65];
    const int blk = blockIdx.x;
    const int tid = threadIdx.x;
    if (blk < 256) {                 // wkvb: w_qkv rows 512..1536 -> bf16
        const int idx = (blk * 256 + tid) * 4;
        float4 v = *(const float4*)(w_qkv + 512 * 256 + idx);
        ushort4 o;
        o.x = f2bf(v.x); o.y = f2bf(v.y); o.z = f2bf(v.z); o.w = f2bf(v.w);
        *(ushort4*)(wkvb + idx) = o;
    } else if (blk < 384) {          // woutb: w_out -> bf16
        const int idx = ((blk - 256) * 256 + tid) * 4;
        float4 v = *(const float4*)(w_out + idx);
        ushort4 o;
        o.x = f2bf(v.x); o.y = f2bf(v.y); o.z = f2bf(v.z); o.w = f2bf(v.w);
        *(ushort4*)(woutb + idx) = o;
    } else {                         // wqT[c][j] = bf16(w_qkv[j][c]), j<512
        const int t = blk - 384;     // 32 tiles: 8 j-tiles x 4 c-tiles
        const int j0 = (t >> 2) * 64, c0 = (t & 3) * 64;
        const int r = tid >> 4, cc = (tid & 15) * 4;
        #pragma unroll
        for (int p = 0; p < 4; ++p) {
            float4 v = *(const float4*)(w_qkv + (j0 + r + p * 16) * 256 + c0 + cc);
            T[r + p * 16][cc + 0] = v.x; T[r + p * 16][cc + 1] = v.y;
            T[r + p * 16][cc + 2] = v.z; T[r + p * 16][cc + 3] = v.w;
        }
        __syncthreads();
        const int c = tid >> 2, jj = (tid & 3) * 16;
        #pragma unroll
        for (int g = 0; g < 4; ++g) {
            ushort4 o;
            o.x = f2bf(T[jj + g * 4 + 0][c]);
            o.y = f2bf(T[jj + g * 4 + 1][c]);
            o.z = f2bf(T[jj + g * 4 + 2][c]);
            o.w = f2bf(T[jj + g * 4 + 3][c]);
            *(ushort4*)(wqT + (c0 + c) * 512 + j0 + jj + g * 4) = o;
        }
    }
}

// ---------------- k0_xt: xbT[b][n][c] = bf16(x[b][c][n]) -------------------
__global__ __launch_bounds__(256) void k0_xt(
    const float* __restrict__ x, unsigned short* __restrict__ xbT)
{
    __shared__ float T[64][65];
    const int tid = threadIdx.x;
    const int n0 = blockIdx.x * 64, c0 = blockIdx.y * 64, b = blockIdx.z;
    const float* xb = x + (size_t)b * 1048576;
    const int cr = tid >> 4, nc = (tid & 15) * 4;
    #pragma unroll
    for (int p = 0; p < 4; ++p) {
        float4 v = *(const float4*)(xb + (size_t)(c0 + cr + p * 16) * 4096 + n0 + nc);
        T[cr + p * 16][nc + 0] = v.x; T[cr + p * 16][nc + 1] = v.y;
        T[cr + p * 16][nc + 2] = v.z; T[cr + p * 16][nc + 3] = v.w;
    }
    __syncthreads();
    const int n = tid >> 2, cc = (tid & 3) * 16;
    unsigned short* dst = xbT + (size_t)b * 1048576 + (size_t)(n0 + n) * 256 + c0 + cc;
    #pragma unroll
    for (int g = 0; g < 4; ++g) {
        ushort4 o;
        o.x = f2bf(T[cc + g * 4 + 0][n]);
        o.y = f2bf(T[cc + g * 4 + 1][n]);
        o.z = f2bf(T[cc + g * 4 + 2][n]);
        o.w = f2bf(T[cc + g * 4 + 3][n]);
        *(ushort4*)(dst + g * 4) = o;
    }
}

// -------- MFMA gemm_bt: C[m][n] = sum_k A[m][k] * B[n][k]  (bf16 in) -------
// 128x128 block tile, BK=32, 4 waves (each 64x64), 16x16x32 bf16 MFMA.
// MODE 0: C bf16, z-strided (k1: kv;  k5: N).
// MODE 1: C f32 + bias[row] (k6: out).
// MODE 2: k3 context — single 128x128 tile, k-slice = blockIdx.x*512.
// MODE 3: k4 M — A=woutb col-block h, B=ctxb[bh], C=Mb col-block h, bf16.
template<int MODE>
__global__ __launch_bounds__(256) void mfma_bt(
    const unsigned short* __restrict__ A0, int lda,
    const unsigned short* __restrict__ B0, int ldb,
    void* __restrict__ C0, int ldc,
    const float* __restrict__ bias, int Kp,
    unsigned long long sAz, unsigned long long sBz, unsigned long long sCz)
{
    __shared__ unsigned short As[128 * 32];
    __shared__ unsigned short Bs[128 * 32];
    const int tid  = threadIdx.x;
    const int w    = tid >> 6, lane = tid & 63;
    const int quad = lane >> 4, l16 = lane & 15;
    const int wm = (w >> 1) * 64, wn = (w & 1) * 64;
    const int z = blockIdx.z;

    const unsigned short* A;
    const unsigned short* B;
    int ks, ke, m0, n0;
    if constexpr (MODE == 2) {
        m0 = 0; n0 = 0;
        ks = blockIdx.x * 512; ke = ks + 512;
        const unsigned long long off =
            ((unsigned long long)(z >> 2) * 1024ull + (unsigned long long)(z & 3) * 128ull) * 4096ull;
        A = A0 + off; B = B0 + off;
    } else if constexpr (MODE == 3) {
        m0 = blockIdx.y * 128; n0 = 0;
        ks = 0; ke = Kp;   // 128
        A = A0 + (unsigned long long)(z & 3) * 128ull + (unsigned long long)m0 * lda;
        B = B0 + (unsigned long long)z * 16384ull;
    } else {
        m0 = blockIdx.y * 128; n0 = blockIdx.x * 128;
        ks = 0; ke = Kp;
        A = A0 + sAz * z + (unsigned long long)m0 * lda;
        B = B0 + sBz * z + (unsigned long long)n0 * ldb;
    }

    // staging: 512 chunks of 16B per tile; wave w handles chunks [w*128, w*128+128)
    const int cA0 = w * 128 + lane;
    const int cA1 = cA0 + 64;
    const unsigned short* gA0 = A + (unsigned long long)(cA0 >> 2) * lda + (cA0 & 3) * 8;
    const unsigned short* gA1 = A + (unsigned long long)(cA1 >> 2) * lda + (cA1 & 3) * 8;
    const unsigned short* gB0 = B + (unsigned long long)(cA0 >> 2) * ldb + (cA0 & 3) * 8;
    const unsigned short* gB1 = B + (unsigned long long)(cA1 >> 2) * ldb + (cA1 & 3) * 8;
    unsigned short* lA0 = As + w * 1024;
    unsigned short* lA1 = As + w * 1024 + 512;
    unsigned short* lB0 = Bs + w * 1024;
    unsigned short* lB1 = Bs + w * 1024 + 512;

    f32x4 acc[4][4] = {};

    for (int k0 = ks; k0 < ke; k0 += 32) {
        gl_lds16(gA0 + k0, lA0);
        gl_lds16(gA1 + k0, lA1);
        gl_lds16(gB0 + k0, lB0);
        gl_lds16(gB1 + k0, lB1);
        __syncthreads();
        frag8 a[4], b[4];
        #pragma unroll
        for (int t = 0; t < 4; ++t) {
            a[t] = *(const frag8*)(As + (wm + t * 16 + l16) * 32 + quad * 8);
            b[t] = *(const frag8*)(Bs + (wn + t * 16 + l16) * 32 + quad * 8);
        }
        #pragma unroll
        for (int mt = 0; mt < 4; ++mt)
            #pragma unroll
            for (int nt = 0; nt < 4; ++nt)
                acc[mt][nt] = __builtin_amdgcn_mfma_f32_16x16x32_bf16(
                    a[mt], b[nt], acc[mt][nt], 0, 0, 0);
        __syncthreads();
    }

    // epilogue: C/D mapping col = lane&15, row = quad*4 + reg  [m91-verified]
    if constexpr (MODE == 0 || MODE == 3) {
        unsigned short* C;
        if constexpr (MODE == 0)
            C = (unsigned short*)C0 + sCz * z + (unsigned long long)m0 * ldc + n0;
        else
            C = (unsigned short*)C0 + (unsigned long long)(z >> 2) * 131072ull
              + (unsigned long long)(z & 3) * 128ull + (unsigned long long)m0 * ldc;
        #pragma unroll
        for (int mt = 0; mt < 4; ++mt) {
            const int row = wm + mt * 16 + quad * 4;
            #pragma unroll
            for (int nt = 0; nt < 4; ++nt) {
                const int col = wn + nt * 16 + l16;
                #pragma unroll
                for (int r = 0; r < 4; ++r)
                    C[(unsigned long long)(row + r) * ldc + col] = f2bf(acc[mt][nt][r]);
            }
        }
    } else if constexpr (MODE == 1) {
        float* C = (float*)C0 + sCz * z + (unsigned long long)m0 * ldc + n0;
        const float* bp = bias + m0;
        #pragma unroll
        for (int mt = 0; mt < 4; ++mt) {
            const int row = wm + mt * 16 + quad * 4;
            #pragma unroll
            for (int nt = 0; nt < 4; ++nt) {
                const int col = wn + nt * 16 + l16;
                #pragma unroll
                for (int r = 0; r < 4; ++r)
                    C[(unsigned long long)(row + r) * ldc + col] = acc[mt][nt][r] + bp[row + r];
            }
        }
    } else {
        float* C = (float*)C0 + ((unsigned long long)blockIdx.x * 32 + z) * 16384ull;
        #pragma unroll
        for (int mt = 0; mt < 4; ++mt) {
            const int row = wm + mt * 16 + quad * 4;
            #pragma unroll
            for (int nt = 0; nt < 4; ++nt) {
                const int col = wn + nt * 16 + l16;
                #pragma unroll
                for (int r = 0; r < 4; ++r)
                    C[(row + r) * 128 + col] = acc[mt][nt][r];
            }
        }
    }
}

// ---------------- k2: in-place softmax over n for k rows (r in [0,512)) ----
__global__ __launch_bounds__(256) void k2_softmax(unsigned short* __restrict__ kv)
{
    __shared__ float red[4];
    const int idx = blockIdx.x;            // b*512 + r
    const int b = idx >> 9, r = idx & 511;
    unsigned short* row = kv + (size_t)(b * 1024 + r) * 4096;
    const int tid = threadIdx.x;
    float v[16];
    #pragma unroll
    for (int g = 0; g < 4; ++g) {
        ushort4 u = *(const ushort4*)(row + g * 1024 + tid * 4);
        v[g * 4 + 0] = bf2f(u.x); v[g * 4 + 1] = bf2f(u.y);
        v[g * 4 + 2] = bf2f(u.z); v[g * 4 + 3] = bf2f(u.w);
    }
    float m = -1e30f;
    #pragma unroll
    for (int i = 0; i < 16; ++i) m = fmaxf(m, v[i]);
    #pragma unroll
    for (int off = 32; off > 0; off >>= 1) m = fmaxf(m, __shfl_down(m, off, 64));
    if ((tid & 63) == 0) red[tid >> 6] = m;
    __syncthreads();
    m = fmaxf(fmaxf(red[0], red[1]), fmaxf(red[2], red[3]));
    __syncthreads();
    float s = 0.f;
    #pragma unroll
    for (int i = 0; i < 16; ++i) { v[i] = __expf(v[i] - m); s += v[i]; }
    #pragma unroll
    for (int off = 32; off > 0; off >>= 1) s += __shfl_down(s, off, 64);
    if ((tid & 63) == 0) red[tid >> 6] = s;
    __syncthreads();
    s = red[0] + red[1] + red[2] + red[3];
    const float inv = 1.0f / s;
    #pragma unroll
    for (int g = 0; g < 4; ++g) {
        ushort4 u;
        u.x = f2bf(v[g * 4 + 0] * inv); u.y = f2bf(v[g * 4 + 1] * inv);
        u.z = f2bf(v[g * 4 + 2] * inv); u.w = f2bf(v[g * 4 + 3] * inv);
        *(ushort4*)(row + g * 1024 + tid * 4) = u;
    }
}

// --------- k3_sum: ctxb[bh][d][e] = bf16( sum_s ctxp[s][bh][d][e] ) --------
__global__ __launch_bounds__(256) void k3_sum(
    const float* __restrict__ ctxp, unsigned short* __restrict__ ctxb)
{
    const int idx = (blockIdx.x * 256 + threadIdx.x) * 4;
    float4 s = make_float4(0.f, 0.f, 0.f, 0.f);
    #pragma unroll
    for (int sl = 0; sl < 8; ++sl) {
        float4 t = *(const float4*)(ctxp + (size_t)sl * 524288 + idx);
        s.x += t.x; s.y += t.y; s.z += t.z; s.w += t.w;
    }
    ushort4 o;
    o.x = f2bf(s.x); o.y = f2bf(s.y); o.z = f2bf(s.z); o.w = f2bf(s.w);
    *(ushort4*)(ctxb + idx) = o;
}

extern "C" void kernel_launch(void* const* d_in, const int* in_sizes, int n_in,
                              void* d_out, int out_size, void* d_ws, size_t ws_size,
                              hipStream_t stream) {
    (void)in_sizes; (void)n_in; (void)out_size; (void)ws_size;
    const float* x     = (const float*)d_in[0];  // f32 [8,256,64,64]
    const float* w_qkv = (const float*)d_in[1];  // f32 [1536,256]
    const float* w_out = (const float*)d_in[2];  // f32 [256,512]
    const float* b_out = (const float*)d_in[3];  // f32 [256]
    float* out = (float*)d_out;                  // f32 [8,256,64,64]

    char* ws = (char*)d_ws;
    unsigned short* kv    = (unsigned short*)ws;                 // 67,108,864
    unsigned short* xbT   = (unsigned short*)(ws + 67108864);    // 16,777,216
    unsigned short* wkvb  = (unsigned short*)(ws + 83886080);    //    524,288
    unsigned short* woutb = (unsigned short*)(ws + 84410368);    //    262,144
    unsigned short* wqT   = (unsigned short*)(ws + 84672512);    //    262,144
    float*          ctxp  = (float*)(ws + 84934656);             // 16,777,216
    unsigned short* ctxb  = (unsigned short*)(ws + 101711872);   //  1,048,576
    unsigned short* Mb    = (unsigned short*)(ws + 102760448);   //  2,097,152
    unsigned short* Nb    = (unsigned short*)(ws + 104857600);   //  1,048,576

    k0_weights<<<dim3(416), 256, 0, stream>>>(w_qkv, w_out, wkvb, woutb, wqT);
    k0_xt<<<dim3(64, 4, 8), 256, 0, stream>>>(x, xbT);
    // k1: kv[b,r,n] = sum_c wkvb[r,c] * xbT[b,n,c]
    mfma_bt<0><<<dim3(32, 8, 8), 256, 0, stream>>>(
        wkvb, 256, xbT, 256, kv, 4096, nullptr, 256,
        0ull, 1048576ull, 4194304ull);
    k2_softmax<<<dim3(4096), 256, 0, stream>>>(kv);
    // k3: ctxp[s,bh,d,e] = sum_{n in slice} Ksm[d,n]*V[e,n]
    mfma_bt<2><<<dim3(8, 1, 32), 256, 0, stream>>>(
        kv, 4096, kv + (size_t)512 * 4096, 4096, ctxp, 128, nullptr, 0,
        0ull, 0ull, 0ull);
    k3_sum<<<dim3(512), 256, 0, stream>>>(ctxp, ctxb);
    // k4: Mb[b][o][h*128+d] = sum_e woutb[o][h*128+e] * ctxb[bh][d][e]
    mfma_bt<3><<<dim3(1, 2, 32), 256, 0, stream>>>(
        woutb, 512, ctxb, 128, Mb, 512, nullptr, 128,
        0ull, 0ull, 0ull);
    // k5: Nb[b][o][c] = sum_j Mb[b][o][j] * wqT[c][j]
    mfma_bt<0><<<dim3(2, 2, 8), 256, 0, stream>>>(
        Mb, 512, wqT, 512, Nb, 256, nullptr, 512,
        131072ull, 0ull, 65536ull);
    // k6: out[b,o,n] = sum_c Nb[b,o,c] * xbT[b,n,c] + b_out[o]
    mfma_bt<1><<<dim3(32, 2, 8), 256, 0, stream>>>(
        Nb, 256, xbT, 256, out, 4096, b_out, 256,
        65536ull, 1048576ull, 1048576ull);
}